// Round 4
// baseline (365.797 us; speedup 1.0000x reference)
//
#include <hip/hip_runtime.h>
#include <hip/hip_bf16.h>

typedef __attribute__((ext_vector_type(8))) short bf16x8;
typedef __attribute__((ext_vector_type(4))) float f32x4;

#define TH 0.01f
#define MFMA(a, b, c) __builtin_amdgcn_mfma_f32_16x16x32_bf16(a, b, c, 0, 0, 0)

constexpr int D = 512, F = 2048;

// LDS map (157952 B dynamic)
constexpr int W1A_O = 0;        // w1 k-half slot A   32 KB
constexpr int W1B_O = 32768;    // w1 k-half slot B   32 KB
constexpr int W2A_O = 65536;    // w2 k-sub slot A    32 KB
constexpr int W2B_O = 98304;    // w2 k-sub slot B    32 KB
constexpr int HS0_O = 131072;   // h tile buf 0        8 KB
constexpr int HS1_O = 139264;   // h tile buf 1        8 KB
constexpr int B1_O  = 147456;   // b1 f32[2048]        8 KB
constexpr int B2_O  = 155648;   // b2 f32[512]         2 KB
constexpr int SPK_O = 157696;   // spike u32[64]
constexpr int LDS_TOTAL = 157952;

static __device__ __forceinline__ short f2bf(float f) {
  union { float f; unsigned u; } v; v.f = f;
  unsigned r = v.u + 0x7FFFu + ((v.u >> 16) & 1u);  // RNE
  return (short)(r >> 16);
}

static __device__ __forceinline__ void gl16(const void* g, char* l) {
  __builtin_amdgcn_global_load_lds(
      (const __attribute__((address_space(1))) unsigned*)g,
      (__attribute__((address_space(3))) unsigned*)l, 16, 0, 0);
}

// ---------------------------------------------------------------------------
// Staged layouts (16B granules, consumed linearly by global_load_lds).
// w1s: 64 regions (chunk*2+half) of 2048 granules. granule g: col=g>>5 (0..63),
//      s=g&31; holds w1[half*256 + (s^(col&7))*8 + j][chunk*64+col], j=0..7.
// w2s: 64 regions (chunk*2+sub) of 2048 granules. granule g: col=g>>2 (0..511),
//      k8=g&3; holds w2[chunk*64+sub*32+k8*8+j][col].
// ---------------------------------------------------------------------------
__global__ void prep_weights(const float* __restrict__ w1, const float* __restrict__ w2,
                             short* __restrict__ w1s, short* __restrict__ w2s) {
  int G = blockIdx.x * 256 + threadIdx.x;
  if (G < 131072) {
    int region = G >> 11, g = G & 2047;
    int chunk = region >> 1, half = region & 1;
    int col = g >> 5, s = g & 31;
    int kbase = half * 256 + (s ^ (col & 7)) * 8;
    int fcol = chunk * 64 + col;
    bf16x8 v;
#pragma unroll
    for (int j = 0; j < 8; ++j) v[j] = f2bf(w1[(size_t)(kbase + j) * F + fcol]);
    *(bf16x8*)(w1s + (size_t)G * 8) = v;
  } else {
    int H = G - 131072;
    int region = H >> 11, g = H & 2047;
    int chunk = region >> 1, sub = region & 1;
    int col = g >> 2, k8 = g & 3;
    int fbase = chunk * 64 + sub * 32 + k8 * 8;
    bf16x8 v;
#pragma unroll
    for (int j = 0; j < 8; ++j) v[j] = f2bf(w2[(size_t)(fbase + j) * D + col]);
    *(bf16x8*)(w2s + (size_t)H * 8) = v;
  }
}

#define ISSUE4(loff, gptr)                                                      \
  do {                                                                          \
    _Pragma("unroll") for (int _t = 0; _t < 4; ++_t)                            \
        gl16((const char*)(gptr) + (size_t)(_t * 512 + tid) * 16,               \
             smem + (loff) + (_t * 512 + tid) * 16);                            \
  } while (0)

#define WAITB                                                   \
  do {                                                          \
    asm volatile("s_waitcnt vmcnt(0) lgkmcnt(0)" ::: "memory"); \
    __builtin_amdgcn_s_barrier();                               \
  } while (0)

// G1: one K-half (256) of h^T = w1^T x : 16 ds_read_b128, 32 MFMA
#define G1_HALF(SLOT, KB)                                                         \
  do {                                                                            \
    const short* _s = (const short*)(smem + (SLOT));                              \
    __builtin_amdgcn_s_setprio(1);                                                \
    _Pragma("unroll") for (int ks = 0; ks < 8; ++ks) {                            \
      int _si = ((ks * 4 + lk) ^ (l15 & 7)) * 8;                                  \
      bf16x8 _w0 = *(const bf16x8*)(_s + (cg * 32 + l15) * 256 + _si);            \
      bf16x8 _w1 = *(const bf16x8*)(_s + (cg * 32 + 16 + l15) * 256 + _si);       \
      hacc[0][0] = MFMA(_w0, xrA[(KB) + ks], hacc[0][0]);                         \
      hacc[0][1] = MFMA(_w0, xrB[(KB) + ks], hacc[0][1]);                         \
      hacc[1][0] = MFMA(_w1, xrA[(KB) + ks], hacc[1][0]);                         \
      hacc[1][1] = MFMA(_w1, xrB[(KB) + ks], hacc[1][1]);                         \
    }                                                                             \
    __builtin_amdgcn_s_setprio(0);                                                \
  } while (0)

// G1: bias+relu+pack hacc -> HS buffer (XOR-swizzled by row&7).
// Row is the GLOBAL x row: rg*32 + rf*16 + l15  (R3 bug: rg*32 was missing).
#define G1_PACK(HBUF, HCH)                                                        \
  do {                                                                            \
    short* _H = (short*)(smem + (HBUF));                                          \
    float4 _b0 = *(const float4*)&b1s[(HCH) * 64 + cg * 32 + lk * 4];             \
    float4 _b1 = *(const float4*)&b1s[(HCH) * 64 + cg * 32 + 16 + lk * 4];        \
    _Pragma("unroll") for (int rf = 0; rf < 2; ++rf) {                            \
      int _row = rg * 32 + rf * 16 + l15;                                         \
      int _m = (_row & 7) << 3;                                                   \
      f32x4 _h0 = hacc[0][rf], _h1 = hacc[1][rf];                                 \
      short4 _p0, _p1;                                                            \
      _p0.x = f2bf(fmaxf(_h0[0] + _b0.x, 0.f));                                   \
      _p0.y = f2bf(fmaxf(_h0[1] + _b0.y, 0.f));                                   \
      _p0.z = f2bf(fmaxf(_h0[2] + _b0.z, 0.f));                                   \
      _p0.w = f2bf(fmaxf(_h0[3] + _b0.w, 0.f));                                   \
      _p1.x = f2bf(fmaxf(_h1[0] + _b1.x, 0.f));                                   \
      _p1.y = f2bf(fmaxf(_h1[1] + _b1.y, 0.f));                                   \
      _p1.z = f2bf(fmaxf(_h1[2] + _b1.z, 0.f));                                   \
      _p1.w = f2bf(fmaxf(_h1[3] + _b1.w, 0.f));                                   \
      *(short4*)&_H[_row * 64 + ((cg * 32 + lk * 4) ^ _m)] = _p0;                 \
      *(short4*)&_H[_row * 64 + ((cg * 32 + 16 + lk * 4) ^ _m)] = _p1;            \
    }                                                                             \
  } while (0)

// G2: one K-sub (32) of out += h w2 : 12 ds_read_b128, 32 MFMA
#define G2_STEP(W2OFF, HOFF, KSL)                                                 \
  do {                                                                            \
    const short* _h = (const short*)(smem + (HOFF));                              \
    const short* _w = (const short*)(smem + (W2OFF));                             \
    bf16x8 _af[4];                                                                \
    _Pragma("unroll") for (int rf = 0; rf < 4; ++rf) {                            \
      int _row = rf * 16 + l15;                                                   \
      _af[rf] = *(const bf16x8*)&_h[_row * 64 +                                   \
                                    (((KSL) * 32 + lk * 8) ^ ((_row & 7) << 3))]; \
    }                                                                             \
    __builtin_amdgcn_s_setprio(1);                                                \
    _Pragma("unroll") for (int fn = 0; fn < 8; ++fn) {                            \
      int _col = C0 + fn * 16 + l15;                                              \
      bf16x8 _bf = *(const bf16x8*)&_w[_col * 32 + lk * 8];                       \
      oacc[0][fn] = MFMA(_af[0], _bf, oacc[0][fn]);                               \
      oacc[1][fn] = MFMA(_af[1], _bf, oacc[1][fn]);                               \
      oacc[2][fn] = MFMA(_af[2], _bf, oacc[2][fn]);                               \
      oacc[3][fn] = MFMA(_af[3], _bf, oacc[3][fn]);                               \
    }                                                                             \
    __builtin_amdgcn_s_setprio(0);                                                \
  } while (0)

__global__ __launch_bounds__(512, 2)
void ffn_fused(const float* __restrict__ x,
               const float* __restrict__ b1,
               const float* __restrict__ b2,
               const char* __restrict__ w1g,
               const char* __restrict__ w2g,
               float* __restrict__ out) {
  extern __shared__ char smem[];
  float*    b1s = (float*)(smem + B1_O);
  float*    b2s = (float*)(smem + B2_O);
  unsigned* spk = (unsigned*)(smem + SPK_O);

  const int tid = threadIdx.x;
  const int lane = tid & 63, wid = tid >> 6;
  const int l15 = lane & 15, lk = lane >> 4;
  const int row0 = blockIdx.x * 64;

  // prologue: stage w1[0] (both halves -> W1A,W1B), all threads
#pragma unroll
  for (int n = 0; n < 8; ++n)
    gl16(w1g + (size_t)(n * 512 + tid) * 16, smem + (n * 512 + tid) * 16);

  if (wid < 4) {
    // ================= G1: producer (GEMM1) =================
    const int rg = wid & 1, cg = wid >> 1;

    // x rows rg*32+l15 / +16 -> registers (B-frags), spike mask
    bf16x8 xrA[16], xrB[16];
    {
      const float* xp0 = x + (size_t)(row0 + rg * 32 + l15) * D + lk * 8;
      const float* xp1 = xp0 + 16 * D;
      bool a0 = false, a1 = false;
#pragma unroll
      for (int ks = 0; ks < 16; ++ks) {
        float4 u0 = *(const float4*)(xp0 + ks * 32);
        float4 u1 = *(const float4*)(xp0 + ks * 32 + 4);
        float4 v0 = *(const float4*)(xp1 + ks * 32);
        float4 v1 = *(const float4*)(xp1 + ks * 32 + 4);
        a0 = a0 | (fabsf(u0.x) > TH) | (fabsf(u0.y) > TH) | (fabsf(u0.z) > TH) |
             (fabsf(u0.w) > TH) | (fabsf(u1.x) > TH) | (fabsf(u1.y) > TH) |
             (fabsf(u1.z) > TH) | (fabsf(u1.w) > TH);
        a1 = a1 | (fabsf(v0.x) > TH) | (fabsf(v0.y) > TH) | (fabsf(v0.z) > TH) |
             (fabsf(v0.w) > TH) | (fabsf(v1.x) > TH) | (fabsf(v1.y) > TH) |
             (fabsf(v1.z) > TH) | (fabsf(v1.w) > TH);
        bf16x8 t0, t1;
        t0[0] = f2bf(u0.x); t0[1] = f2bf(u0.y); t0[2] = f2bf(u0.z); t0[3] = f2bf(u0.w);
        t0[4] = f2bf(u1.x); t0[5] = f2bf(u1.y); t0[6] = f2bf(u1.z); t0[7] = f2bf(u1.w);
        t1[0] = f2bf(v0.x); t1[1] = f2bf(v0.y); t1[2] = f2bf(v0.z); t1[3] = f2bf(v0.w);
        t1[4] = f2bf(v1.x); t1[5] = f2bf(v1.y); t1[6] = f2bf(v1.z); t1[7] = f2bf(v1.w);
        xrA[ks] = t0; xrB[ks] = t1;
      }
      int m = (a0 ? 1 : 0) | (a1 ? 2 : 0);
      m |= __shfl_xor(m, 16, 64);
      m |= __shfl_xor(m, 32, 64);
      if (lane < 16) {
        spk[rg * 32 + lane] = (unsigned)(m & 1);
        spk[rg * 32 + 16 + lane] = (unsigned)((m >> 1) & 1);
      }
    }
    WAITB;  // #1: w1[0] + biases ready

    f32x4 hacc[2][2];
    // pre-A: compute h[0] half0; issue w2[0]s0
    ISSUE4(W2A_O, w2g);
#pragma unroll
    for (int a = 0; a < 2; ++a)
#pragma unroll
      for (int b = 0; b < 2; ++b) hacc[a][b] = f32x4{0.f, 0.f, 0.f, 0.f};
    G1_HALF(W1A_O, 0);
    WAITB;  // #2
    // pre-B: h[0] half1 + pack -> HS0; issue w1[1]h0
    ISSUE4(W1A_O, w1g + 2 * 32768);
    G1_HALF(W1B_O, 8);
    G1_PACK(HS0_O, 0);
    WAITB;  // #3

    for (int i = 0; i < 32; ++i) {
      // ---- phase A: h[i+1] half0 from W1A ----
      if (i <= 30) ISSUE4(W1B_O, w1g + (size_t)((i + 1) * 2 + 1) * 32768);
      ISSUE4(W2B_O, w2g + (size_t)(i * 2 + 1) * 32768);
      if (i <= 30) {
#pragma unroll
        for (int a = 0; a < 2; ++a)
#pragma unroll
          for (int b = 0; b < 2; ++b) hacc[a][b] = f32x4{0.f, 0.f, 0.f, 0.f};
        G1_HALF(W1A_O, 0);
      }
      WAITB;
      // ---- phase B: half1 from W1B + pack ----
      if (i <= 29) ISSUE4(W1A_O, w1g + (size_t)((i + 2) * 2) * 32768);
      if (i <= 30) ISSUE4(W2A_O, w2g + (size_t)((i + 1) * 2) * 32768);
      if (i <= 30) {
        G1_HALF(W1B_O, 8);
        if ((i + 1) & 1) G1_PACK(HS1_O, i + 1);
        else             G1_PACK(HS0_O, i + 1);
      }
      WAITB;
    }
  } else {
    // ================= G2: consumer (GEMM2) =================
    const int C0 = (wid - 4) * 128;
    const int t2 = tid - 256;  // 0..255

    // biases -> LDS
    *(float4*)&b1s[t2 * 8]     = *(const float4*)&b1[t2 * 8];
    *(float4*)&b1s[t2 * 8 + 4] = *(const float4*)&b1[t2 * 8 + 4];
    if (t2 < 128) *(float4*)&b2s[t2 * 4] = *(const float4*)&b2[t2 * 4];
    WAITB;  // #1
    ISSUE4(W2A_O, w2g);
    WAITB;  // #2
    ISSUE4(W1A_O, w1g + 2 * 32768);
    WAITB;  // #3

    f32x4 oacc[4][8];
#pragma unroll
    for (int a = 0; a < 4; ++a)
#pragma unroll
      for (int b = 0; b < 8; ++b) oacc[a][b] = f32x4{0.f, 0.f, 0.f, 0.f};

    for (int i = 0; i < 32; ++i) {
      // ---- phase A: k-sub0 (W2A), h[i] ----
      if (i <= 30) ISSUE4(W1B_O, w1g + (size_t)((i + 1) * 2 + 1) * 32768);
      ISSUE4(W2B_O, w2g + (size_t)(i * 2 + 1) * 32768);
      if (i & 1) G2_STEP(W2A_O, HS1_O, 0);
      else       G2_STEP(W2A_O, HS0_O, 0);
      WAITB;
      // ---- phase B: k-sub1 (W2B) ----
      if (i <= 29) ISSUE4(W1A_O, w1g + (size_t)((i + 2) * 2) * 32768);
      if (i <= 30) ISSUE4(W2A_O, w2g + (size_t)((i + 1) * 2) * 32768);
      if (i & 1) G2_STEP(W2B_O, HS1_O, 1);
      else       G2_STEP(W2B_O, HS0_O, 1);
      WAITB;
    }

    // epilogue: + b2, spike mask, store (this wave owns all 64 rows x its 128 cols)
    unsigned sv[4][4];
#pragma unroll
    for (int rf = 0; rf < 4; ++rf)
#pragma unroll
      for (int rr = 0; rr < 4; ++rr) sv[rf][rr] = spk[rf * 16 + lk * 4 + rr];
#pragma unroll
    for (int fn = 0; fn < 8; ++fn) {
      int col = C0 + fn * 16 + l15;
      float bias = b2s[col];
#pragma unroll
      for (int rf = 0; rf < 4; ++rf) {
#pragma unroll
        for (int rr = 0; rr < 4; ++rr) {
          int row = rf * 16 + lk * 4 + rr;
          float v = oacc[rf][fn][rr] + bias;
          out[(size_t)(row0 + row) * D + col] = sv[rf][rr] ? v : 0.f;
        }
      }
    }
  }
}

extern "C" void kernel_launch(void* const* d_in, const int* in_sizes, int n_in,
                              void* d_out, int out_size, void* d_ws, size_t ws_size,
                              hipStream_t stream) {
  const float* x  = (const float*)d_in[0];
  const float* w1 = (const float*)d_in[1];
  const float* b1 = (const float*)d_in[2];
  const float* w2 = (const float*)d_in[3];
  const float* b2 = (const float*)d_in[4];
  float* out = (float*)d_out;

  short* w1staged = (short*)d_ws;               // 2 MB
  short* w2staged = w1staged + (size_t)D * F;   // 2 MB

  prep_weights<<<1024, 256, 0, stream>>>(w1, w2, w1staged, w2staged);

  (void)hipFuncSetAttribute((const void*)ffn_fused,
                            hipFuncAttributeMaxDynamicSharedMemorySize, LDS_TOTAL);
  int M = out_size / D;  // 32768
  ffn_fused<<<M / 64, 512, LDS_TOTAL, stream>>>(x, b1, b2, (const char*)w1staged,
                                                (const char*)w2staged, out);
}

// Round 5
// 165.755 us; speedup vs baseline: 2.2069x; 2.2069x over previous
//
#include <hip/hip_runtime.h>
#include <hip/hip_bf16.h>

typedef __attribute__((ext_vector_type(8))) short bf16x8;
typedef __attribute__((ext_vector_type(4))) float f32x4;

#define TH 0.01f
#define MFMA(a, b, c) __builtin_amdgcn_mfma_f32_16x16x32_bf16(a, b, c, 0, 0, 0)

constexpr int D = 512, F = 2048, BM = 128, NC = 32;

// LDS map (158208 B dynamic)
constexpr int W1A_O = 0;        // w1 k-half slot A (k 0..255 of chunk)   32 KB
constexpr int W1B_O = 32768;    // w1 k-half slot B (k 256..511)          32 KB
constexpr int W2A_O = 65536;    // w2 k-sub slot A (hk 0..31)             32 KB
constexpr int W2B_O = 98304;    // w2 k-sub slot B (hk 32..63)            32 KB
constexpr int HS_O  = 131072;   // h tile [128 rows][64] bf16, XOR-swz    16 KB
constexpr int B1_O  = 147456;   // b1 f32[2048]                            8 KB
constexpr int B2_O  = 155648;   // b2 f32[512]                             2 KB
constexpr int SPK_O = 157696;   // spike u32[128]                        512 B
constexpr int LDS_TOTAL = 158208;

static __device__ __forceinline__ short f2bf(float f) {
  union { float f; unsigned u; } v; v.f = f;
  unsigned r = v.u + 0x7FFFu + ((v.u >> 16) & 1u);  // RNE
  return (short)(r >> 16);
}

static __device__ __forceinline__ void gl16(const void* g, char* l) {
  __builtin_amdgcn_global_load_lds(
      (const __attribute__((address_space(1))) unsigned*)g,
      (__attribute__((address_space(3))) unsigned*)l, 16, 0, 0);
}

// ---------------------------------------------------------------------------
// Staged layouts (16B granules, consumed linearly by global_load_lds; XOR
// swizzle baked into the SOURCE permutation, applied again on ds_read).
// w1s: 64 regions (chunk*2+half) x 32KB. granule g: hcol=g>>5, s=g&31;
//      holds w1[half*256 + (s^(hcol&7))*8 + j][chunk*64+hcol], j=0..7.
// w2s: 64 regions (chunk*2+sub) x 32KB. granule g: col=g>>2, kg=g&3;
//      holds w2[chunk*64 + sub*32 + (kg^((col>>1)&3))*8 + j][col].
// ---------------------------------------------------------------------------
__global__ void prep_weights(const float* __restrict__ w1, const float* __restrict__ w2,
                             short* __restrict__ w1s, short* __restrict__ w2s) {
  int G = blockIdx.x * 256 + threadIdx.x;
  if (G < 131072) {
    int region = G >> 11, g = G & 2047;
    int chunk = region >> 1, half = region & 1;
    int col = g >> 5, s = g & 31;
    int kbase = half * 256 + (s ^ (col & 7)) * 8;
    int fcol = chunk * 64 + col;
    bf16x8 v;
#pragma unroll
    for (int j = 0; j < 8; ++j) v[j] = f2bf(w1[(size_t)(kbase + j) * F + fcol]);
    *(bf16x8*)(w1s + (size_t)G * 8) = v;
  } else {
    int H = G - 131072;
    int region = H >> 11, g = H & 2047;
    int chunk = region >> 1, sub = region & 1;
    int col = g >> 2, kg = g & 3;
    int fbase = chunk * 64 + sub * 32 + (kg ^ ((col >> 1) & 3)) * 8;
    bf16x8 v;
#pragma unroll
    for (int j = 0; j < 8; ++j) v[j] = f2bf(w2[(size_t)(fbase + j) * D + col]);
    *(bf16x8*)(w2s + (size_t)H * 8) = v;
  }
}

#define ISSUE4(loff, gptr)                                                      \
  do {                                                                          \
    _Pragma("unroll") for (int _t = 0; _t < 4; ++_t)                            \
        gl16((const char*)(gptr) + (size_t)(_t * 512 + tid) * 16,               \
             smem + (loff) + (_t * 512 + tid) * 16);                            \
  } while (0)

// G1 phase: 8 k-steps on one w1 half-slot; 32 ds_read_b128 + 32 MFMA.
#define G1_HALF(SLOT, KB)                                                       \
  do {                                                                          \
    const short* _ws = (const short*)(smem + (SLOT));                           \
    __builtin_amdgcn_s_setprio(1);                                              \
    _Pragma("unroll") for (int s = 0; s < 8; ++s) {                             \
      _Pragma("unroll") for (int f = 0; f < 4; ++f) {                           \
        int _hcol = f * 16 + l15;                                               \
        int _off = _hcol * 256 + (((s * 4 + lk) ^ (_hcol & 7)) << 3);           \
        hacc[f] = MFMA(*(const bf16x8*)(_ws + _off), xr[(KB) + s], hacc[f]);    \
      }                                                                         \
    }                                                                           \
    __builtin_amdgcn_s_setprio(0);                                              \
  } while (0)

// G2 phase: one k-sub; 1 h-frag read + 32 w2-frag reads + 32 MFMA.
#define G2_SUB(W2OFF, SUB)                                                      \
  do {                                                                          \
    const short* _h = (const short*)(smem + HS_O);                              \
    const short* _w = (const short*)(smem + (W2OFF));                           \
    bf16x8 _af = *(const bf16x8*)(_h + hrow * 64 +                              \
                                  ((((SUB)*4 + lk) ^ (hrow & 7)) << 3));        \
    __builtin_amdgcn_s_setprio(1);                                              \
    _Pragma("unroll") for (int fn = 0; fn < 32; ++fn)                           \
      oacc[fn] = MFMA(_af, *(const bf16x8*)(_w + fn * 512 + w2base), oacc[fn]); \
    __builtin_amdgcn_s_setprio(0);                                              \
  } while (0)

__global__ __launch_bounds__(512, 2)
void ffn_fused(const float* __restrict__ x,
               const float* __restrict__ b1,
               const float* __restrict__ b2,
               const char* __restrict__ w1g,
               const char* __restrict__ w2g,
               float* __restrict__ out) {
  extern __shared__ char smem[];
  float*    b1s = (float*)(smem + B1_O);
  float*    b2s = (float*)(smem + B2_O);
  unsigned* spk = (unsigned*)(smem + SPK_O);

  const int tid = threadIdx.x;
  const int lane = tid & 63, wid = tid >> 6;
  const int l15 = lane & 15, lk = lane >> 4;
  const int row0 = blockIdx.x * BM;

  // ---- prologue: issue chunk-0 slots W1A, W1B, W2A (12 loads/thread) ----
  ISSUE4(W1A_O, w1g);
  ISSUE4(W1B_O, w1g + 32768);
  ISSUE4(W2A_O, w2g);

  // biases -> LDS (keeps ordinary VMEM out of the main loop entirely)
  *(float4*)&b1s[tid * 4] = *(const float4*)&b1[tid * 4];
  if (tid < 128) *(float4*)&b2s[tid * 4] = *(const float4*)&b2[tid * 4];

  // x rows wid*16+l15 -> registers (MFMA B-frags) + spike mask
  bf16x8 xr[16];
  {
    const float* xp = x + (size_t)(row0 + wid * 16 + l15) * D + lk * 8;
    bool any = false;
#pragma unroll
    for (int s = 0; s < 16; ++s) {
      float4 f0 = *(const float4*)(xp + s * 32);
      float4 f1 = *(const float4*)(xp + s * 32 + 4);
      any = any | (fabsf(f0.x) > TH) | (fabsf(f0.y) > TH) | (fabsf(f0.z) > TH) |
            (fabsf(f0.w) > TH) | (fabsf(f1.x) > TH) | (fabsf(f1.y) > TH) |
            (fabsf(f1.z) > TH) | (fabsf(f1.w) > TH);
      bf16x8 v;
      v[0] = f2bf(f0.x); v[1] = f2bf(f0.y); v[2] = f2bf(f0.z); v[3] = f2bf(f0.w);
      v[4] = f2bf(f1.x); v[5] = f2bf(f1.y); v[6] = f2bf(f1.z); v[7] = f2bf(f1.w);
      xr[s] = v;
    }
    unsigned a = any ? 1u : 0u;
    a |= __shfl_xor(a, 16, 64);
    a |= __shfl_xor(a, 32, 64);
    if (lane < 16) spk[wid * 16 + lane] = a;
  }

  f32x4 oacc[32];
#pragma unroll
  for (int n = 0; n < 32; ++n) oacc[n] = f32x4{0.f, 0.f, 0.f, 0.f};

  const int w2base = l15 * 32 + ((lk ^ ((l15 >> 1) & 3)) << 3);  // + fn*512
  const int hrow = wid * 16 + l15;
  const int hxor = (hrow & 7) << 3;

  // ---- main loop: 32 chunks x 4 phases; every phase: counted-vmcnt wait,
  //      barrier, issue one 32KB slot (4 loads/thread), 32 MFMA/wave. ----
  for (int i = 0; i < NC; ++i) {
    f32x4 hacc[4];

    // P1: GEMM1 half0 (W1A[i]); issue W2B[i]
    asm volatile("s_waitcnt vmcnt(8) lgkmcnt(0)" ::: "memory");
    __builtin_amdgcn_s_barrier();
    ISSUE4(W2B_O, w2g + (size_t)(i * 2 + 1) * 32768);
#pragma unroll
    for (int f = 0; f < 4; ++f) hacc[f] = f32x4{0.f, 0.f, 0.f, 0.f};
    G1_HALF(W1A_O, 0);

    // P2: GEMM1 half1 (W1B[i]); issue W1A[i+1]; pack h
    asm volatile("s_waitcnt vmcnt(8) lgkmcnt(0)" ::: "memory");
    __builtin_amdgcn_s_barrier();
    if (i < NC - 1) ISSUE4(W1A_O, w1g + (size_t)((i + 1) * 2) * 32768);
    G1_HALF(W1B_O, 8);
    {
      short* hsl = (short*)(smem + HS_O);
#pragma unroll
      for (int f = 0; f < 4; ++f) {
        float4 bv = *(const float4*)&b1s[i * 64 + f * 16 + lk * 4];
        short4 p;
        p.x = f2bf(fmaxf(hacc[f][0] + bv.x, 0.f));
        p.y = f2bf(fmaxf(hacc[f][1] + bv.y, 0.f));
        p.z = f2bf(fmaxf(hacc[f][2] + bv.z, 0.f));
        p.w = f2bf(fmaxf(hacc[f][3] + bv.w, 0.f));
        *(short4*)&hsl[hrow * 64 + ((f * 16 + lk * 4) ^ hxor)] = p;
      }
    }

    // P3: GEMM2 sub0 (W2A[i]); issue W1B[i+1]
    if (i < NC - 1) asm volatile("s_waitcnt vmcnt(8) lgkmcnt(0)" ::: "memory");
    else            asm volatile("s_waitcnt vmcnt(4) lgkmcnt(0)" ::: "memory");
    __builtin_amdgcn_s_barrier();
    if (i < NC - 1) ISSUE4(W1B_O, w1g + (size_t)((i + 1) * 2 + 1) * 32768);
    G2_SUB(W2A_O, 0);

    // P4: GEMM2 sub1 (W2B[i]); issue W2A[i+1]
    if (i < NC - 1) asm volatile("s_waitcnt vmcnt(8) lgkmcnt(0)" ::: "memory");
    else            asm volatile("s_waitcnt vmcnt(0) lgkmcnt(0)" ::: "memory");
    __builtin_amdgcn_s_barrier();
    if (i < NC - 1) ISSUE4(W2A_O, w2g + (size_t)((i + 1) * 2) * 32768);
    G2_SUB(W2B_O, 1);
  }

  // ---- epilogue: + b2, spike mask, store ----
  unsigned sv[4];
#pragma unroll
  for (int r = 0; r < 4; ++r) sv[r] = spk[wid * 16 + lk * 4 + r];
#pragma unroll
  for (int fn = 0; fn < 32; ++fn) {
    int col = fn * 16 + l15;
    float bias = b2s[col];
#pragma unroll
    for (int r = 0; r < 4; ++r) {
      int row = wid * 16 + lk * 4 + r;
      float v = oacc[fn][r] + bias;
      out[(size_t)(row0 + row) * D + col] = sv[r] ? v : 0.f;
    }
  }
}

extern "C" void kernel_launch(void* const* d_in, const int* in_sizes, int n_in,
                              void* d_out, int out_size, void* d_ws, size_t ws_size,
                              hipStream_t stream) {
  const float* x  = (const float*)d_in[0];
  const float* w1 = (const float*)d_in[1];
  const float* b1 = (const float*)d_in[2];
  const float* w2 = (const float*)d_in[3];
  const float* b2 = (const float*)d_in[4];
  float* out = (float*)d_out;

  short* w1staged = (short*)d_ws;               // 2 MB
  short* w2staged = w1staged + (size_t)D * F;   // 2 MB

  prep_weights<<<1024, 256, 0, stream>>>(w1, w2, w1staged, w2staged);

  (void)hipFuncSetAttribute((const void*)ffn_fused,
                            hipFuncAttributeMaxDynamicSharedMemorySize, LDS_TOTAL);
  int M = out_size / D;  // 32768
  ffn_fused<<<M / BM, 512, LDS_TOTAL, stream>>>(x, b1, b2, (const char*)w1staged,
                                                (const char*)w2staged, out);
}